// Round 5
// baseline (86.854 us; speedup 1.0000x reference)
//
#include <hip/hip_runtime.h>
#include <math.h>

// RBF kernel matrix: cov[i][j] = exp(lv - 0.5*||(x_i - xx_j) * inv_scale||^2)
// Log2-domain expansion (v_exp_f32 = exp2 applied directly):
//   W[d]   = inv_scale[d]^2 * log2(e)
//   B[j,d] = xx[j,d] * W[d]
//   c[j]   = lv*log2e - 0.5 * sum_d xx[j,d]^2 * W[d]
//   h_i    = -0.5 * sum_d x[i,d]^2 * W[d]
//   cov    = exp2(h_i + c_j + sum_d x[i,d] * B[j,d])
//
// R5 theory: stores and loads share vmcnt. Any vector load issued after a
// store batch forces draining those stores (waitcnt waits on oldest-first),
// serializing the store stream -> observed ~21us (3.2 TB/s) plateau across
// R0/R1/R2/R4 vs the fill's proven 5.9 TB/s. Fix: LOAD EVERYTHING FIRST.
// Per block: prologue loads w, 4 xx columns, all 8 x rows; compute all
// res[8][4] in registers; then 8 back-to-back 1KB wave-stores; endpgm.
// Zero vector loads after the first store -> store pipe free-flows.

constexpr int D   = 8;   // feature dim (fixed by reference)
constexpr int TJ  = 4;   // columns per thread -> one float4 store
constexpr int BLK = 256; // threads per block
constexpr int RPB = 8;   // rows per block (all computed before any store)

typedef float f32x4 __attribute__((ext_vector_type(4)));

__global__ __launch_bounds__(BLK) void rbf_kernel(
    const float* __restrict__ x,         // [N, D]
    const float* __restrict__ xx,        // [M, D]
    const float* __restrict__ log_scale, // [D]
    const float* __restrict__ log_var,   // [1]
    float* __restrict__ out,             // [N, M]
    int N, int M)
{
    const int j0 = blockIdx.x * (BLK * TJ) + threadIdx.x * TJ;
    const int i0 = blockIdx.y * RPB;
    if (j0 + TJ > M || i0 + RPB > N) return;  // exact for 4096; safety only

    // ---- Prologue: ALL loads happen here, before any store. ----
    constexpr float LOG2E = 1.4426950408889634f;
    float w[D];
#pragma unroll
    for (int d = 0; d < D; ++d) {
        const float s = __expf(-log_scale[d]);  // 1/scale
        w[d] = s * s * LOG2E;                   // log2e folded in
    }
    const float lv2 = log_var[0] * LOG2E;

    // x rows for the whole block (wave-uniform addresses, L1/L2-hot).
    float4 xr[RPB][2];
#pragma unroll
    for (int r = 0; r < RPB; ++r) {
        const float4* px = (const float4*)(x + (size_t)(i0 + r) * D);
        xr[r][0] = px[0];
        xr[r][1] = px[1];
    }

    // Per-column state: B[jj][d] = xx*W, c[jj] = lv2 - 0.5*sum(xx^2*W).
    float B[TJ][D], c[TJ];
#pragma unroll
    for (int jj = 0; jj < TJ; ++jj) {
        const float4* p = (const float4*)(xx + (size_t)(j0 + jj) * D);
        const float4 a = p[0], b = p[1];
        const float v[D] = {a.x, a.y, a.z, a.w, b.x, b.y, b.z, b.w};
        float q = 0.f;
#pragma unroll
        for (int d = 0; d < D; ++d) {
            B[jj][d] = v[d] * w[d];
            q = fmaf(v[d], B[jj][d], q);
        }
        c[jj] = fmaf(-0.5f, q, lv2);
    }

    // ---- Compute phase: all RPB x TJ outputs into registers. ----
    float res[RPB][TJ];
#pragma unroll
    for (int r = 0; r < RPB; ++r) {
        const float4 a = xr[r][0], b = xr[r][1];
        const float xv[D] = {a.x, a.y, a.z, a.w, b.x, b.y, b.z, b.w};
        float q = 0.f;
#pragma unroll
        for (int d = 0; d < D; ++d) q = fmaf(xv[d] * w[d], xv[d], q);
        const float h = -0.5f * q;
#pragma unroll
        for (int jj = 0; jj < TJ; ++jj) {
            float e = h + c[jj];
#pragma unroll
            for (int d = 0; d < D; ++d) e = fmaf(xv[d], B[jj][d], e);
            res[r][jj] = __builtin_amdgcn_exp2f(e);
        }
    }

    // ---- Store phase: RPB back-to-back 1KB wave-stores, then exit. ----
#pragma unroll
    for (int r = 0; r < RPB; ++r) {
        const f32x4 o = {res[r][0], res[r][1], res[r][2], res[r][3]};
        *(f32x4*)(out + (size_t)(i0 + r) * M + j0) = o;
    }
}

extern "C" void kernel_launch(void* const* d_in, const int* in_sizes, int n_in,
                              void* d_out, int out_size, void* d_ws, size_t ws_size,
                              hipStream_t stream) {
    const float* x  = (const float*)d_in[0];
    const float* xx = (const float*)d_in[1];
    const float* ls = (const float*)d_in[2];
    const float* lv = (const float*)d_in[3];
    float* out      = (float*)d_out;

    const int N = in_sizes[0] / D;
    const int M = in_sizes[1] / D;

    dim3 block(BLK, 1, 1);
    dim3 grid((M + BLK * TJ - 1) / (BLK * TJ), (N + RPB - 1) / RPB, 1);
    rbf_kernel<<<grid, block, 0, stream>>>(x, xx, ls, lv, out, N, M);
}